// Round 9
// baseline (940.453 us; speedup 1.0000x reference)
//
#include <hip/hip_runtime.h>
#include <hip/hip_bf16.h>

#define NR 4096

// ===== REP instrumentation (R9 attribution round): each kernel repeats its
// body REP times; per-kernel true time = dur_us / REP. Bodies are idempotent
// (deterministic functions of inputs), so outputs are unchanged. =====
#define REP_GATE 12
#define REP_PREP 6
#define REP_G0 8
#define REP_G1 6
#define REP_G2 8

typedef float f32x4 __attribute__((ext_vector_type(4)));
typedef __bf16 bf16x8 __attribute__((ext_vector_type(8)));

typedef __attribute__((address_space(1))) unsigned int u32_g;
typedef __attribute__((address_space(3))) unsigned int u32_l;

__device__ __forceinline__ void gl_lds16(const void* g, void* l) {
  __builtin_amdgcn_global_load_lds((const u32_g*)g, (u32_l*)l, 16, 0, 0);
}

// =====================================================================
// Staged operand layout (bf16): logical Z[rows][K], row-blocks RB of 256,
// K-tiles T of 64:  chunk(row,k) at
//   off = ((RB*KT + T)*2 + s)*16384 + g*4096 + (row&255)*16 + e*2
// B cols expert-interleaved: p = (o>>5)*256+((o>>3)&3)*64+(e>>1)*16+(o&7)*2+(e&1)
// =====================================================================

// ---- 256-thread weight tile stage ----
__device__ void wtile256(const float* __restrict__ w, __hip_bfloat16* __restrict__ out,
                         int Kin, int KT, int Oin, int oblk, int u, char* LDS)
{
  int kt = u % KT;
  int yy = u / KT;
  int e = yy / oblk;
  int o0 = (yy - e * oblk) << 6;
  int k0 = kt << 6;
  float* t = (float*)LDS;  // [64][65]
  int tid = threadIdx.x;
  int tx = tid & 63, ty = tid >> 6;  // 64 x 4
#pragma unroll
  for (int i = 0; i < 16; ++i) {
    int k = k0 + ty + i * 4;
    int o = o0 + tx;
    float v = (k < Kin && o < Oin) ? w[((size_t)e * Kin + k) * Oin + o] : 0.f;
    t[(ty + i * 4) * 65 + tx] = v;
  }
  __syncthreads();
#pragma unroll
  for (int it = 0; it < 2; ++it) {
    int c = it * 256 + tid;
    int j = c & 63, sg = c >> 6;
    bf16x8 v;
#pragma unroll
    for (int e8 = 0; e8 < 8; ++e8) v[e8] = (__bf16)t[(sg * 8 + e8) * 65 + j];
    int o = o0 + j;
    int p = ((o >> 5) << 8) + (((o >> 3) & 3) << 6) + ((e >> 1) << 4) + ((o & 7) << 1) + (e & 1);
    size_t off = (((size_t)(p >> 8) * KT + kt) * 2 + (sg >> 2)) * 16384
               + (size_t)(sg & 3) * 4096 + (size_t)(p & 255) * 16;
    *(bf16x8*)((char*)out + off) = v;
  }
}

// ---- x0 staging unit: 256 chunks ----
__device__ void x0unit(int u, const float* __restrict__ cond, const float* __restrict__ lat,
                       __hip_bfloat16* __restrict__ out)
{
  int c = u * 256 + threadIdx.x;
  int RB = c / 10240;
  int r1 = c - RB * 10240;
  int T = r1 >> 11, r2 = r1 & 2047;
  int n = RB * 256 + (r2 & 255);
  int k0 = T * 64 + (r2 >> 10) * 32 + ((r2 >> 8) & 3) * 8;
  bf16x8 v;
#pragma unroll
  for (int e = 0; e < 8; ++e) {
    int k = k0 + e;
    float f = (k < 219) ? cond[(size_t)n * 219 + k]
            : (k < 283) ? lat[(size_t)n * 64 + (k - 219)] : 0.f;
    v[e] = (__bf16)f;
  }
  *(bf16x8*)((char*)out + (size_t)c * 16) = v;
}

// ---- x1 latent unit (T=8 of KT=9): 256 chunks ----
__device__ void x1lat(int u, const float* __restrict__ lat, __hip_bfloat16* __restrict__ out)
{
  int c = u * 256 + threadIdx.x;  // 0..32767
  int RB = c >> 11, r2 = c & 2047;
  int n = RB * 256 + (r2 & 255);
  int k0 = (r2 >> 10) * 32 + ((r2 >> 8) & 3) * 8;
  bf16x8 v;
#pragma unroll
  for (int e = 0; e < 8; ++e) v[e] = (__bf16)lat[(size_t)n * 64 + k0 + e];
  size_t off = ((size_t)RB * 9 + 8) * 32768 + (size_t)r2 * 16;
  *(bf16x8*)((char*)out + off) = v;
}

// ---- prepS: ALL staging, one wide kernel, every block independent ----
__global__ __launch_bounds__(256) void prepS(
    const float* __restrict__ latent, const float* __restrict__ condition,
    const float* __restrict__ w0, const float* __restrict__ w1, const float* __restrict__ w2,
    __hip_bfloat16* x0s, __hip_bfloat16* x1s,
    __hip_bfloat16* w0s, __hip_bfloat16* w1s, __hip_bfloat16* w2s)
{
  __shared__ __align__(16) char LDS[64 * 65 * 4];
  int b = blockIdx.x;
#pragma unroll 1
  for (int rep = 0; rep < REP_PREP; ++rep) {
    if (b < 320)       wtile256(w0, w0s, 283, 5, 512, 8, b, LDS);
    else if (b < 896)  wtile256(w1, w1s, 576, 9, 512, 8, b - 320, LDS);
    else if (b < 1088) wtile256(w2, w2s, 512, 8, 171, 3, b - 896, LDS);
    else if (b < 1152) {
      int u0 = b - 1088;
      x1lat(u0, latent, x1s);
      x1lat(u0 + 64, latent, x1s);
    } else {
      x0unit(b - 1152, condition, latent, x0s);  // 640 units
    }
    __syncthreads();
  }
}

// ---- gate kernel: LDS-cached weights, 4x4 register-blocked, exact fp32 ----
__global__ __launch_bounds__(256) void gate_k(
    const float* __restrict__ phs, const float* __restrict__ lat,
    const float* __restrict__ gw1, const float* __restrict__ gb1,
    const float* __restrict__ gw2, const float* __restrict__ gb2,
    const float* __restrict__ gw3, const float* __restrict__ gb3,
    float* __restrict__ coeff)
{
  __shared__ __align__(16) float wL[128 * 128];   // 64KB, reused w1 -> w2
  __shared__ __align__(16) float g0T[104 * 36];   // [k][row]
  __shared__ __align__(16) float h1T[128 * 36];
  __shared__ __align__(16) float h2T[128 * 36];
  __shared__ __align__(16) float w3L[128 * 8];
  const int tid = threadIdx.x;
  const int n0 = blockIdx.x * 32;

#pragma unroll 1
  for (int rep = 0; rep < REP_GATE; ++rep) {
    __syncthreads();
    for (int i = tid; i < 104 * 32; i += 256) {
      int k = i >> 5, r = i & 31;
      g0T[k * 36 + r] = (k < 40) ? phs[(size_t)(n0 + r) * 40 + k]
                                 : lat[(size_t)(n0 + r) * 64 + (k - 40)];
    }
    for (int i = tid; i < 104 * 32; i += 256) ((float4*)wL)[i] = ((const float4*)gw1)[i];
    ((float4*)w3L)[tid] = ((const float4*)gw3)[tid];
    __syncthreads();

    const int ct = tid & 31, rt = tid >> 5;
    const int c0 = ct << 2, r0 = rt << 2;

    // layer 1
    {
      f32x4 a0 = {}, a1 = {}, a2 = {}, a3 = {};
      for (int k = 0; k < 104; ++k) {
        f32x4 g = *(const f32x4*)&g0T[k * 36 + r0];
        f32x4 w = *(const f32x4*)&wL[k * 128 + c0];
        a0 += g * w.x; a1 += g * w.y; a2 += g * w.z; a3 += g * w.w;
      }
      f32x4 bb = *(const f32x4*)&gb1[c0];
      a0 += bb.x; a1 += bb.y; a2 += bb.z; a3 += bb.w;
#pragma unroll
      for (int j = 0; j < 4; ++j) {
        a0[j] = a0[j] > 0.f ? a0[j] : expm1f(a0[j]);
        a1[j] = a1[j] > 0.f ? a1[j] : expm1f(a1[j]);
        a2[j] = a2[j] > 0.f ? a2[j] : expm1f(a2[j]);
        a3[j] = a3[j] > 0.f ? a3[j] : expm1f(a3[j]);
      }
      *(f32x4*)&h1T[(c0 + 0) * 36 + r0] = a0;
      *(f32x4*)&h1T[(c0 + 1) * 36 + r0] = a1;
      *(f32x4*)&h1T[(c0 + 2) * 36 + r0] = a2;
      *(f32x4*)&h1T[(c0 + 3) * 36 + r0] = a3;
    }
    __syncthreads();
    for (int i = tid; i < 128 * 32; i += 256) ((float4*)wL)[i] = ((const float4*)gw2)[i];
    __syncthreads();

    // layer 2
    {
      f32x4 a0 = {}, a1 = {}, a2 = {}, a3 = {};
      for (int k = 0; k < 128; ++k) {
        f32x4 g = *(const f32x4*)&h1T[k * 36 + r0];
        f32x4 w = *(const f32x4*)&wL[k * 128 + c0];
        a0 += g * w.x; a1 += g * w.y; a2 += g * w.z; a3 += g * w.w;
      }
      f32x4 bb = *(const f32x4*)&gb2[c0];
      a0 += bb.x; a1 += bb.y; a2 += bb.z; a3 += bb.w;
#pragma unroll
      for (int j = 0; j < 4; ++j) {
        a0[j] = a0[j] > 0.f ? a0[j] : expm1f(a0[j]);
        a1[j] = a1[j] > 0.f ? a1[j] : expm1f(a1[j]);
        a2[j] = a2[j] > 0.f ? a2[j] : expm1f(a2[j]);
        a3[j] = a3[j] > 0.f ? a3[j] : expm1f(a3[j]);
      }
      *(f32x4*)&h2T[(c0 + 0) * 36 + r0] = a0;
      *(f32x4*)&h2T[(c0 + 1) * 36 + r0] = a1;
      *(f32x4*)&h2T[(c0 + 2) * 36 + r0] = a2;
      *(f32x4*)&h2T[(c0 + 3) * 36 + r0] = a3;
    }
    __syncthreads();

    // layer 3 + softmax
    {
      int row = tid >> 3, e = tid & 7;
      float acc = 0.f;
      for (int k = 0; k < 128; ++k) acc += h2T[k * 36 + row] * w3L[k * 8 + e];
      float lgt = acc + gb3[e];
      float m = lgt;
      m = fmaxf(m, __shfl_xor(m, 1));
      m = fmaxf(m, __shfl_xor(m, 2));
      m = fmaxf(m, __shfl_xor(m, 4));
      float ex = expf(lgt - m);
      float s = ex;
      s += __shfl_xor(s, 1);
      s += __shfl_xor(s, 2);
      s += __shfl_xor(s, 4);
      coeff[(size_t)(n0 + row) * 8 + e] = ex / s;
    }
  }
}

// ---- 8-phase K-tile (verified R3-R8) ----
#define MFMA_PHASE(NH)                                                                  \
  _Pragma("unroll") for (int fm = 0; fm < 8; ++fm) {                                    \
    acc[fm][2*(NH)]   = __builtin_amdgcn_mfma_f32_16x16x32_bf16(a[fm], b0, acc[fm][2*(NH)],   0, 0, 0); \
    acc[fm][2*(NH)+1] = __builtin_amdgcn_mfma_f32_16x16x32_bf16(a[fm], b1, acc[fm][2*(NH)+1], 0, 0, 0); \
  }

template <bool ST>
__device__ __forceinline__ void ktile(const char* cL, char* nL,
                                      const char* gA, const char* gB,
                                      int tid, int wid, int aoff, int boff,
                                      f32x4 (&acc)[8][4])
{
  bf16x8 a[8], b0, b1;
  const char* pa = cL;
  const char* pb = cL + 32768;
#pragma unroll
  for (int fm = 0; fm < 8; ++fm) a[fm] = *(const bf16x8*)(pa + aoff + fm * 256);
  b0 = *(const bf16x8*)(pb + boff + 0);
  b1 = *(const bf16x8*)(pb + boff + 256);
  if (ST) {
    gl_lds16(gA + tid * 16,        nL + (wid << 10));
    gl_lds16(gA + 8192 + tid * 16, nL + 8192 + (wid << 10));
  }
  __builtin_amdgcn_s_barrier();
  __builtin_amdgcn_s_setprio(1);
  MFMA_PHASE(0);
  __builtin_amdgcn_s_setprio(0);
  __builtin_amdgcn_s_barrier();
  b0 = *(const bf16x8*)(pb + boff + 512);
  b1 = *(const bf16x8*)(pb + boff + 768);
  if (ST) {
    gl_lds16(gB + tid * 16,        nL + 32768 + (wid << 10));
    gl_lds16(gB + 8192 + tid * 16, nL + 32768 + 8192 + (wid << 10));
  }
  __builtin_amdgcn_s_barrier();
  __builtin_amdgcn_s_setprio(1);
  MFMA_PHASE(1);
  __builtin_amdgcn_s_setprio(0);
  if (ST) asm volatile("s_waitcnt vmcnt(4)" ::: "memory");
  else    asm volatile("s_waitcnt vmcnt(0)" ::: "memory");
  __builtin_amdgcn_s_barrier();
  pa = cL + 16384; pb = cL + 32768 + 16384;
#pragma unroll
  for (int fm = 0; fm < 8; ++fm) a[fm] = *(const bf16x8*)(pa + aoff + fm * 256);
  b0 = *(const bf16x8*)(pb + boff + 0);
  b1 = *(const bf16x8*)(pb + boff + 256);
  if (ST) {
    gl_lds16(gA + 16384 + tid * 16,        nL + 16384 + (wid << 10));
    gl_lds16(gA + 16384 + 8192 + tid * 16, nL + 16384 + 8192 + (wid << 10));
  }
  __builtin_amdgcn_s_barrier();
  __builtin_amdgcn_s_setprio(1);
  MFMA_PHASE(0);
  __builtin_amdgcn_s_setprio(0);
  __builtin_amdgcn_s_barrier();
  b0 = *(const bf16x8*)(pb + boff + 512);
  b1 = *(const bf16x8*)(pb + boff + 768);
  if (ST) {
    gl_lds16(gB + 16384 + tid * 16,        nL + 32768 + 16384 + (wid << 10));
    gl_lds16(gB + 16384 + 8192 + tid * 16, nL + 32768 + 16384 + 8192 + (wid << 10));
  }
  __builtin_amdgcn_s_barrier();
  __builtin_amdgcn_s_setprio(1);
  MFMA_PHASE(1);
  __builtin_amdgcn_s_setprio(0);
  if (ST) asm volatile("s_waitcnt vmcnt(4)" ::: "memory");
  __builtin_amdgcn_s_barrier();
}

// ---- pure GEMM kernel (256x256 tile, fused expert-blend epilogue) ----
template <int KT, int KTD, int MODE, int BYG, int REP>
__global__ __launch_bounds__(512, 2) void gemm_k(
    const __hip_bfloat16* __restrict__ Ap, const __hip_bfloat16* __restrict__ Bp,
    const float* __restrict__ coeff, const float* __restrict__ bias,
    __hip_bfloat16* __restrict__ dstS, float* __restrict__ dstF)
{
  __shared__ __align__(16) char lds[131072];
  const int bid = blockIdx.x;
  const int xcd = bid & 7, l = bid >> 3;
  const int bx = ((xcd & 3) << 2) + (l & 3);
  const int by = (xcd >> 2) * BYG + (l >> 2);
  const int tid = threadIdx.x;
  const int lane = tid & 63;
  const int wid = tid >> 6;
  const int wr = wid >> 2, wc = wid & 3;
  const int l15 = lane & 15, lg = lane >> 4;
  const int aoff = lg * 4096 + wr * 2048 + l15 * 16;
  const int boff = lg * 4096 + wc * 1024 + l15 * 16;

  const char* aG = (const char*)Ap + (size_t)bx * KT * 32768;
  const char* bG = (const char*)Bp + (size_t)by * KT * 32768;

#pragma unroll 1
  for (int rep = 0; rep < REP; ++rep) {
    f32x4 acc[8][4] = {};

    {
      char* L = lds;
      gl_lds16(aG + tid * 16,                 L + (wid << 10));
      gl_lds16(aG + 8192 + tid * 16,          L + 8192 + (wid << 10));
      gl_lds16(bG + tid * 16,                 L + 32768 + (wid << 10));
      gl_lds16(bG + 8192 + tid * 16,          L + 32768 + 8192 + (wid << 10));
      gl_lds16(aG + 16384 + tid * 16,         L + 16384 + (wid << 10));
      gl_lds16(aG + 16384 + 8192 + tid * 16,  L + 16384 + 8192 + (wid << 10));
      gl_lds16(bG + 16384 + tid * 16,         L + 32768 + 16384 + (wid << 10));
      gl_lds16(bG + 16384 + 8192 + tid * 16,  L + 32768 + 16384 + 8192 + (wid << 10));
      asm volatile("s_waitcnt vmcnt(4)" ::: "memory");
      __builtin_amdgcn_s_barrier();
    }

    for (int t = 0; t < KT; ++t) {
      const char* cL = lds + ((t & 1) << 16);
      char* nL = lds + (((t + 1) & 1) << 16);
      const char* gA = aG + (size_t)(t + 1) * 32768;
      const char* gB = bG + (size_t)(t + 1) * 32768;
      if (t + 1 < KT) ktile<true>(cL, nL, gA, gB, tid, wid, aoff, boff, acc);
      else            ktile<false>(cL, nL, gA, gB, tid, wid, aoff, boff, acc);
    }

    // fused expert-blend epilogue (coeff transposed [8][258]: conflict-free)
    float* cl2 = (float*)lds;
    {
#pragma unroll
      for (int i = 0; i < 4; ++i) {
        int idx = i * 512 + tid;
        int e = idx & 7, n = idx >> 3;
        cl2[e * 258 + n] = coeff[((size_t)bx * 256 + n) * 8 + e];
      }
    }
    __syncthreads();
    const int e0 = lane & 1;
    const int o_loc = (wc << 3) + (l15 >> 1);

    if (MODE == 0) {
      float* tb = (float*)(lds + 8448);  // [256][33] f32
      float bb[4];
#pragma unroll
      for (int fn = 0; fn < 4; ++fn) bb[fn] = bias[(fn * 2 + e0) * 512 + by * 32 + o_loc];
#pragma unroll
      for (int fm = 0; fm < 8; ++fm) {
#pragma unroll
        for (int r = 0; r < 4; ++r) {
          int n_loc = wr * 128 + fm * 16 + (lg << 2) + r;
          float s = 0.f;
#pragma unroll
          for (int fn = 0; fn < 4; ++fn)
            s += cl2[(fn * 2 + e0) * 258 + n_loc] * (acc[fm][fn][r] + bb[fn]);
          s += __shfl_xor(s, 1);
          s = s > 0.f ? s : expm1f(s);
          if ((lane & 1) == (fm & 1)) tb[n_loc * 33 + o_loc] = s;
        }
      }
      __syncthreads();
#pragma unroll
      for (int it = 0; it < 2; ++it) {
        int ch = it * 512 + tid;
        int n_loc = ch & 255, c = ch >> 8;
        const float* p = &tb[n_loc * 33 + c * 8];
        bf16x8 v;
#pragma unroll
        for (int j = 0; j < 8; ++j) v[j] = (__bf16)p[j];
        size_t off = (((size_t)bx * KTD + (by >> 1)) * 2 + (by & 1)) * 16384
                   + (size_t)c * 4096 + (size_t)n_loc * 16;
        *(bf16x8*)((char*)dstS + off) = v;
      }
    } else {
      const int o_g = by * 32 + o_loc;
      if (o_g < 171) {
        float bb[4];
#pragma unroll
        for (int fn = 0; fn < 4; ++fn) bb[fn] = bias[(fn * 2 + e0) * 171 + o_g];
#pragma unroll
        for (int fm = 0; fm < 8; ++fm) {
#pragma unroll
          for (int r = 0; r < 4; ++r) {
            int n_loc = wr * 128 + fm * 16 + (lg << 2) + r;
            float s = 0.f;
#pragma unroll
            for (int fn = 0; fn < 4; ++fn)
              s += cl2[(fn * 2 + e0) * 258 + n_loc] * (acc[fm][fn][r] + bb[fn]);
            s += __shfl_xor(s, 1);
            if ((lane & 1) == (fm & 1))
              dstF[(size_t)(bx * 256 + n_loc) * 171 + o_g] = s;
          }
        }
      }
    }
    __syncthreads();  // LDS reuse boundary between reps
  }
}

// ---------------- launch ----------------
extern "C" void kernel_launch(void* const* d_in, const int* in_sizes, int n_in,
                              void* d_out, int out_size, void* d_ws, size_t ws_size,
                              hipStream_t stream)
{
  const float* latent    = (const float*)d_in[0];
  const float* condition = (const float*)d_in[1];
  const float* phase     = (const float*)d_in[2];
  const float* gw1 = (const float*)d_in[3];
  const float* gb1 = (const float*)d_in[4];
  const float* gw2 = (const float*)d_in[5];
  const float* gb2 = (const float*)d_in[6];
  const float* gw3 = (const float*)d_in[7];
  const float* gb3 = (const float*)d_in[8];
  const float* w0  = (const float*)d_in[9];
  const float* b0  = (const float*)d_in[10];
  const float* w1  = (const float*)d_in[11];
  const float* b1  = (const float*)d_in[12];
  const float* w2  = (const float*)d_in[13];
  const float* b2  = (const float*)d_in[14];

  float* out   = (float*)d_out;
  float* coeff = out + (size_t)NR * 171;

  char* ws = (char*)d_ws;
  __hip_bfloat16* x0s = (__hip_bfloat16*)ws; ws += (size_t)16 * 5 * 32768;
  __hip_bfloat16* x1s = (__hip_bfloat16*)ws; ws += (size_t)16 * 9 * 32768;
  __hip_bfloat16* x2s = (__hip_bfloat16*)ws; ws += (size_t)16 * 8 * 32768;
  __hip_bfloat16* w0s = (__hip_bfloat16*)ws; ws += (size_t)16 * 5 * 32768;
  __hip_bfloat16* w1s = (__hip_bfloat16*)ws; ws += (size_t)16 * 9 * 32768;
  __hip_bfloat16* w2s = (__hip_bfloat16*)ws; ws += (size_t)6 * 8 * 32768;

  gate_k<<<128, 256, 0, stream>>>(phase, latent, gw1, gb1, gw2, gb2, gw3, gb3, coeff);
  prepS<<<1792, 256, 0, stream>>>(latent, condition, w0, w1, w2,
                                  x0s, x1s, w0s, w1s, w2s);
  gemm_k<5, 9, 0, 8, REP_G0><<<256, 512, 0, stream>>>(x0s, w0s, coeff, b0, x1s, nullptr);
  gemm_k<9, 8, 0, 8, REP_G1><<<256, 512, 0, stream>>>(x1s, w1s, coeff, b1, x2s, nullptr);
  gemm_k<8, 0, 1, 3, REP_G2><<<96, 512, 0, stream>>>(x2s, w2s, coeff, b2, nullptr, out);
}

// Round 10
// 103.235 us; speedup vs baseline: 9.1099x; 9.1099x over previous
//
#include <hip/hip_runtime.h>
#include <hip/hip_bf16.h>

#define NR 4096

typedef float f32x4 __attribute__((ext_vector_type(4)));
typedef __bf16 bf16x8 __attribute__((ext_vector_type(8)));

typedef __attribute__((address_space(1))) unsigned int u32_g;
typedef __attribute__((address_space(3))) unsigned int u32_l;

__device__ __forceinline__ void gl_lds16(const void* g, void* l) {
  __builtin_amdgcn_global_load_lds((const u32_g*)g, (u32_l*)l, 16, 0, 0);
}

// =====================================================================
// Staged operand layout (bf16): logical Z[rows][K], row-blocks RB of 256,
// K-tiles T of 64:  chunk(row,k) at
//   off = ((RB*KT + T)*2 + s)*16384 + g*4096 + (row&255)*16 + e*2
// B cols expert-interleaved: p = (o>>5)*256+((o>>3)&3)*64+(e>>1)*16+(o&7)*2+(e&1)
//   => in-tile: e = fn*2+(l15&1), o = by*32 + wc*8 + (l15>>1)
// =====================================================================

// ---- 256-thread weight tile stage ----
__device__ void wtile256(const float* __restrict__ w, __hip_bfloat16* __restrict__ out,
                         int Kin, int KT, int Oin, int oblk, int u, char* LDS)
{
  int kt = u % KT;
  int yy = u / KT;
  int e = yy / oblk;
  int o0 = (yy - e * oblk) << 6;
  int k0 = kt << 6;
  float* t = (float*)LDS;  // [64][65]
  int tid = threadIdx.x;
  int tx = tid & 63, ty = tid >> 6;  // 64 x 4
#pragma unroll
  for (int i = 0; i < 16; ++i) {
    int k = k0 + ty + i * 4;
    int o = o0 + tx;
    float v = (k < Kin && o < Oin) ? w[((size_t)e * Kin + k) * Oin + o] : 0.f;
    t[(ty + i * 4) * 65 + tx] = v;
  }
  __syncthreads();
#pragma unroll
  for (int it = 0; it < 2; ++it) {
    int c = it * 256 + tid;
    int j = c & 63, sg = c >> 6;
    bf16x8 v;
#pragma unroll
    for (int e8 = 0; e8 < 8; ++e8) v[e8] = (__bf16)t[(sg * 8 + e8) * 65 + j];
    int o = o0 + j;
    int p = ((o >> 5) << 8) + (((o >> 3) & 3) << 6) + ((e >> 1) << 4) + ((o & 7) << 1) + (e & 1);
    size_t off = (((size_t)(p >> 8) * KT + kt) * 2 + (sg >> 2)) * 16384
               + (size_t)(sg & 3) * 4096 + (size_t)(p & 255) * 16;
    *(bf16x8*)((char*)out + off) = v;
  }
}

// ---- x0 staging unit: 256 chunks ----
__device__ void x0unit(int u, const float* __restrict__ cond, const float* __restrict__ lat,
                       __hip_bfloat16* __restrict__ out)
{
  int c = u * 256 + threadIdx.x;
  int RB = c / 10240;
  int r1 = c - RB * 10240;
  int T = r1 >> 11, r2 = r1 & 2047;
  int n = RB * 256 + (r2 & 255);
  int k0 = T * 64 + (r2 >> 10) * 32 + ((r2 >> 8) & 3) * 8;
  bf16x8 v;
#pragma unroll
  for (int e = 0; e < 8; ++e) {
    int k = k0 + e;
    float f = (k < 219) ? cond[(size_t)n * 219 + k]
            : (k < 283) ? lat[(size_t)n * 64 + (k - 219)] : 0.f;
    v[e] = (__bf16)f;
  }
  *(bf16x8*)((char*)out + (size_t)c * 16) = v;
}

// ---- x1 latent unit (T=8 of KT=9): 256 chunks ----
__device__ void x1lat(int u, const float* __restrict__ lat, __hip_bfloat16* __restrict__ out)
{
  int c = u * 256 + threadIdx.x;  // 0..32767
  int RB = c >> 11, r2 = c & 2047;
  int n = RB * 256 + (r2 & 255);
  int k0 = (r2 >> 10) * 32 + ((r2 >> 8) & 3) * 8;
  bf16x8 v;
#pragma unroll
  for (int e = 0; e < 8; ++e) v[e] = (__bf16)lat[(size_t)n * 64 + k0 + e];
  size_t off = ((size_t)RB * 9 + 8) * 32768 + (size_t)r2 * 16;
  *(bf16x8*)((char*)out + off) = v;
}

// ---- prepS: ALL staging, one wide kernel, every block independent ----
__global__ __launch_bounds__(256) void prepS(
    const float* __restrict__ latent, const float* __restrict__ condition,
    const float* __restrict__ w0, const float* __restrict__ w1, const float* __restrict__ w2,
    __hip_bfloat16* x0s, __hip_bfloat16* x1s,
    __hip_bfloat16* w0s, __hip_bfloat16* w1s, __hip_bfloat16* w2s)
{
  __shared__ __align__(16) char LDS[64 * 65 * 4];
  int b = blockIdx.x;
  if (b < 320)       wtile256(w0, w0s, 283, 5, 512, 8, b, LDS);
  else if (b < 896)  wtile256(w1, w1s, 576, 9, 512, 8, b - 320, LDS);
  else if (b < 1088) wtile256(w2, w2s, 512, 8, 171, 3, b - 896, LDS);
  else if (b < 1152) {
    int u0 = b - 1088;
    x1lat(u0, latent, x1s);
    x1lat(u0 + 64, latent, x1s);
  } else {
    x0unit(b - 1152, condition, latent, x0s);  // 640 units
  }
}

// ---- gate kernel: LDS-cached weights, 4x4 register-blocked, exact fp32 ----
__global__ __launch_bounds__(256) void gate_k(
    const float* __restrict__ phs, const float* __restrict__ lat,
    const float* __restrict__ gw1, const float* __restrict__ gb1,
    const float* __restrict__ gw2, const float* __restrict__ gb2,
    const float* __restrict__ gw3, const float* __restrict__ gb3,
    float* __restrict__ coeff)
{
  __shared__ __align__(16) float wL[128 * 128];   // 64KB, reused w1 -> w2
  __shared__ __align__(16) float g0T[104 * 36];   // [k][row]
  __shared__ __align__(16) float h1T[128 * 36];
  __shared__ __align__(16) float h2T[128 * 36];
  __shared__ __align__(16) float w3L[128 * 8];
  const int tid = threadIdx.x;
  const int n0 = blockIdx.x * 32;

  for (int i = tid; i < 104 * 32; i += 256) {
    int k = i >> 5, r = i & 31;
    g0T[k * 36 + r] = (k < 40) ? phs[(size_t)(n0 + r) * 40 + k]
                               : lat[(size_t)(n0 + r) * 64 + (k - 40)];
  }
  for (int i = tid; i < 104 * 32; i += 256) ((float4*)wL)[i] = ((const float4*)gw1)[i];
  ((float4*)w3L)[tid] = ((const float4*)gw3)[tid];
  __syncthreads();

  const int ct = tid & 31, rt = tid >> 5;
  const int c0 = ct << 2, r0 = rt << 2;

  // layer 1
  {
    f32x4 a0 = {}, a1 = {}, a2 = {}, a3 = {};
    for (int k = 0; k < 104; ++k) {
      f32x4 g = *(const f32x4*)&g0T[k * 36 + r0];
      f32x4 w = *(const f32x4*)&wL[k * 128 + c0];
      a0 += g * w.x; a1 += g * w.y; a2 += g * w.z; a3 += g * w.w;
    }
    f32x4 bb = *(const f32x4*)&gb1[c0];
    a0 += bb.x; a1 += bb.y; a2 += bb.z; a3 += bb.w;
#pragma unroll
    for (int j = 0; j < 4; ++j) {
      a0[j] = a0[j] > 0.f ? a0[j] : expm1f(a0[j]);
      a1[j] = a1[j] > 0.f ? a1[j] : expm1f(a1[j]);
      a2[j] = a2[j] > 0.f ? a2[j] : expm1f(a2[j]);
      a3[j] = a3[j] > 0.f ? a3[j] : expm1f(a3[j]);
    }
    *(f32x4*)&h1T[(c0 + 0) * 36 + r0] = a0;
    *(f32x4*)&h1T[(c0 + 1) * 36 + r0] = a1;
    *(f32x4*)&h1T[(c0 + 2) * 36 + r0] = a2;
    *(f32x4*)&h1T[(c0 + 3) * 36 + r0] = a3;
  }
  __syncthreads();
  for (int i = tid; i < 128 * 32; i += 256) ((float4*)wL)[i] = ((const float4*)gw2)[i];
  __syncthreads();

  // layer 2
  {
    f32x4 a0 = {}, a1 = {}, a2 = {}, a3 = {};
    for (int k = 0; k < 128; ++k) {
      f32x4 g = *(const f32x4*)&h1T[k * 36 + r0];
      f32x4 w = *(const f32x4*)&wL[k * 128 + c0];
      a0 += g * w.x; a1 += g * w.y; a2 += g * w.z; a3 += g * w.w;
    }
    f32x4 bb = *(const f32x4*)&gb2[c0];
    a0 += bb.x; a1 += bb.y; a2 += bb.z; a3 += bb.w;
#pragma unroll
    for (int j = 0; j < 4; ++j) {
      a0[j] = a0[j] > 0.f ? a0[j] : expm1f(a0[j]);
      a1[j] = a1[j] > 0.f ? a1[j] : expm1f(a1[j]);
      a2[j] = a2[j] > 0.f ? a2[j] : expm1f(a2[j]);
      a3[j] = a3[j] > 0.f ? a3[j] : expm1f(a3[j]);
    }
    *(f32x4*)&h2T[(c0 + 0) * 36 + r0] = a0;
    *(f32x4*)&h2T[(c0 + 1) * 36 + r0] = a1;
    *(f32x4*)&h2T[(c0 + 2) * 36 + r0] = a2;
    *(f32x4*)&h2T[(c0 + 3) * 36 + r0] = a3;
  }
  __syncthreads();

  // layer 3 + softmax
  {
    int row = tid >> 3, e = tid & 7;
    float acc = 0.f;
    for (int k = 0; k < 128; ++k) acc += h2T[k * 36 + row] * w3L[k * 8 + e];
    float lgt = acc + gb3[e];
    float m = lgt;
    m = fmaxf(m, __shfl_xor(m, 1));
    m = fmaxf(m, __shfl_xor(m, 2));
    m = fmaxf(m, __shfl_xor(m, 4));
    float ex = expf(lgt - m);
    float s = ex;
    s += __shfl_xor(s, 1);
    s += __shfl_xor(s, 2);
    s += __shfl_xor(s, 4);
    coeff[(size_t)(n0 + row) * 8 + e] = ex / s;
  }
}

// ---- GEMM: 256x256 tile, BARRIER-LIGHT loop (2 barriers/tile), dbuf, ----
// ---- counted vmcnt with full-tile prefetch distance, fused blend.    ----
// MODE 0 -> staged bf16 next-layer activations; MODE 1 -> fp32 final out.
template <int KT, int KTD, int MODE, int BYG>
__global__ __launch_bounds__(512, 2) void gemm_k(
    const __hip_bfloat16* __restrict__ Ap, const __hip_bfloat16* __restrict__ Bp,
    const float* __restrict__ coeff, const float* __restrict__ bias,
    __hip_bfloat16* __restrict__ dstS, float* __restrict__ dstF)
{
  __shared__ __align__(16) char lds[131072];   // 2 x (A 32KB + B 32KB)
  const int bid = blockIdx.x;
  const int xcd = bid & 7, l = bid >> 3;
  const int bx = ((xcd & 3) << 2) + (l & 3);
  const int by = (xcd >> 2) * BYG + (l >> 2);
  const int tid = threadIdx.x;
  const int lane = tid & 63;
  const int wid = tid >> 6;
  const int wr = wid >> 2, wc = wid & 3;
  const int l15 = lane & 15, lg = lane >> 4;
  const int aoff = lg * 4096 + wr * 2048 + l15 * 16;
  const int boff = lg * 4096 + wc * 1024 + l15 * 16;

  const char* aG = (const char*)Ap + (size_t)bx * KT * 32768;
  const char* bG = (const char*)Bp + (size_t)by * KT * 32768;

  // stage one 64KB K-tile (A 32KB + B 32KB) into L; 8 gl_lds16 calls
#define STAGE(T, L)                                                        \
  {                                                                        \
    const char* gA_ = aG + (size_t)(T) * 32768;                            \
    const char* gB_ = bG + (size_t)(T) * 32768;                            \
    _Pragma("unroll") for (int h = 0; h < 4; ++h)                          \
      gl_lds16(gA_ + h * 8192 + tid * 16, (L) + h * 8192 + (wid << 10));   \
    _Pragma("unroll") for (int h = 0; h < 4; ++h)                          \
      gl_lds16(gB_ + h * 8192 + tid * 16, (L) + 32768 + h * 8192 + (wid << 10)); \
  }

  f32x4 acc[8][4] = {};

  // prologue: tiles 0 and 1 in flight; wait tile 0 (drop to 8 outstanding)
  STAGE(0, lds);
  STAGE(1, lds + 65536);
  asm volatile("s_waitcnt vmcnt(8)" ::: "memory");
  __builtin_amdgcn_s_barrier();

#pragma unroll 1
  for (int t = 0; t < KT; ++t) {
    char* cL = lds + ((t & 1) << 16);
    const char* pa = cL;
    const char* pb = cL + 32768;
#pragma unroll
    for (int s = 0; s < 2; ++s) {
      bf16x8 a[8], b[4];
#pragma unroll
      for (int fm = 0; fm < 8; ++fm) a[fm] = *(const bf16x8*)(pa + aoff + fm * 256);
#pragma unroll
      for (int nf = 0; nf < 4; ++nf) b[nf] = *(const bf16x8*)(pb + boff + nf * 256);
#pragma unroll
      for (int fm = 0; fm < 8; ++fm)
#pragma unroll
        for (int nf = 0; nf < 4; ++nf)
          acc[fm][nf] = __builtin_amdgcn_mfma_f32_16x16x32_bf16(a[fm], b[nf], acc[fm][nf], 0, 0, 0);
      pa += 16384; pb += 16384;
    }
    if (t + 1 < KT) {
      __builtin_amdgcn_s_barrier();   // all waves done reading cL
      if (t + 2 < KT) {
        STAGE(t + 2, cL);             // prefetch into the buffer just freed
        asm volatile("s_waitcnt vmcnt(8)" ::: "memory");   // tile t+1 landed
      } else {
        asm volatile("s_waitcnt vmcnt(0)" ::: "memory");   // last tile landed
      }
      __builtin_amdgcn_s_barrier();   // everyone's vmcnt satisfied -> t+1 ready
    }
  }
#undef STAGE
  __syncthreads();  // protect lds reuse by epilogue

  // ---- fused expert-blend epilogue (coeff transposed [8][258]: conflict-free) ----
  float* cl2 = (float*)lds;
  {
#pragma unroll
    for (int i = 0; i < 4; ++i) {
      int idx = i * 512 + tid;
      int e = idx & 7, n = idx >> 3;
      cl2[e * 258 + n] = coeff[((size_t)bx * 256 + n) * 8 + e];
    }
  }
  __syncthreads();
  const int e0 = lane & 1;
  const int o_loc = (wc << 3) + (l15 >> 1);

  if (MODE == 0) {
    float* tb = (float*)(lds + 8448);  // [256][33] f32
    float bb[4];
#pragma unroll
    for (int fn = 0; fn < 4; ++fn) bb[fn] = bias[(fn * 2 + e0) * 512 + by * 32 + o_loc];
#pragma unroll
    for (int fm = 0; fm < 8; ++fm) {
#pragma unroll
      for (int r = 0; r < 4; ++r) {
        int n_loc = wr * 128 + fm * 16 + (lg << 2) + r;
        float s = 0.f;
#pragma unroll
        for (int fn = 0; fn < 4; ++fn)
          s += cl2[(fn * 2 + e0) * 258 + n_loc] * (acc[fm][fn][r] + bb[fn]);
        s += __shfl_xor(s, 1);
        s = s > 0.f ? s : expm1f(s);
        if ((lane & 1) == (fm & 1)) tb[n_loc * 33 + o_loc] = s;
      }
    }
    __syncthreads();
#pragma unroll
    for (int it = 0; it < 2; ++it) {
      int ch = it * 512 + tid;
      int n_loc = ch & 255, c = ch >> 8;
      const float* p = &tb[n_loc * 33 + c * 8];
      bf16x8 v;
#pragma unroll
      for (int j = 0; j < 8; ++j) v[j] = (__bf16)p[j];
      size_t off = (((size_t)bx * KTD + (by >> 1)) * 2 + (by & 1)) * 16384
                 + (size_t)c * 4096 + (size_t)n_loc * 16;
      *(bf16x8*)((char*)dstS + off) = v;
    }
  } else {
    const int o_g = by * 32 + o_loc;
    if (o_g < 171) {
      float bb[4];
#pragma unroll
      for (int fn = 0; fn < 4; ++fn) bb[fn] = bias[(fn * 2 + e0) * 171 + o_g];
#pragma unroll
      for (int fm = 0; fm < 8; ++fm) {
#pragma unroll
        for (int r = 0; r < 4; ++r) {
          int n_loc = wr * 128 + fm * 16 + (lg << 2) + r;
          float s = 0.f;
#pragma unroll
          for (int fn = 0; fn < 4; ++fn)
            s += cl2[(fn * 2 + e0) * 258 + n_loc] * (acc[fm][fn][r] + bb[fn]);
          s += __shfl_xor(s, 1);
          if ((lane & 1) == (fm & 1))
            dstF[(size_t)(bx * 256 + n_loc) * 171 + o_g] = s;
        }
      }
    }
  }
}

// ---------------- launch ----------------
extern "C" void kernel_launch(void* const* d_in, const int* in_sizes, int n_in,
                              void* d_out, int out_size, void* d_ws, size_t ws_size,
                              hipStream_t stream)
{
  const float* latent    = (const float*)d_in[0];
  const float* condition = (const float*)d_in[1];
  const float* phase     = (const float*)d_in[2];
  const float* gw1 = (const float*)d_in[3];
  const float* gb1 = (const float*)d_in[4];
  const float* gw2 = (const float*)d_in[5];
  const float* gb2 = (const float*)d_in[6];
  const float* gw3 = (const float*)d_in[7];
  const float* gb3 = (const float*)d_in[8];
  const float* w0  = (const float*)d_in[9];
  const float* b0  = (const float*)d_in[10];
  const float* w1  = (const float*)d_in[11];
  const float* b1  = (const float*)d_in[12];
  const float* w2  = (const float*)d_in[13];
  const float* b2  = (const float*)d_in[14];

  float* out   = (float*)d_out;
  float* coeff = out + (size_t)NR * 171;

  char* ws = (char*)d_ws;
  __hip_bfloat16* x0s = (__hip_bfloat16*)ws; ws += (size_t)16 * 5 * 32768;
  __hip_bfloat16* x1s = (__hip_bfloat16*)ws; ws += (size_t)16 * 9 * 32768;
  __hip_bfloat16* x2s = (__hip_bfloat16*)ws; ws += (size_t)16 * 8 * 32768;
  __hip_bfloat16* w0s = (__hip_bfloat16*)ws; ws += (size_t)16 * 5 * 32768;
  __hip_bfloat16* w1s = (__hip_bfloat16*)ws; ws += (size_t)16 * 9 * 32768;
  __hip_bfloat16* w2s = (__hip_bfloat16*)ws; ws += (size_t)6 * 8 * 32768;

  // K1: gate (exact fp32, LDS-cached weights)
  gate_k<<<128, 256, 0, stream>>>(phase, latent, gw1, gb1, gw2, gb2, gw3, gb3, coeff);

  // K2: all staging in parallel
  prepS<<<1792, 256, 0, stream>>>(latent, condition, w0, w1, w2,
                                  x0s, x1s, w0s, w1s, w2s);

  // K3-K5: barrier-light fused GEMMs
  gemm_k<5, 9, 0, 8><<<256, 512, 0, stream>>>(x0s, w0s, coeff, b0, x1s, nullptr);
  gemm_k<9, 8, 0, 8><<<256, 512, 0, stream>>>(x1s, w1s, coeff, b1, x2s, nullptr);
  gemm_k<8, 0, 1, 3><<<96, 512, 0, stream>>>(x2s, w2s, coeff, b2, nullptr, out);
}

// Round 11
// 93.238 us; speedup vs baseline: 10.0866x; 1.1072x over previous
//
#include <hip/hip_runtime.h>
#include <hip/hip_bf16.h>

#define NR 4096

typedef float f32x4 __attribute__((ext_vector_type(4)));
typedef __bf16 bf16x8 __attribute__((ext_vector_type(8)));

typedef __attribute__((address_space(1))) unsigned int u32_g;
typedef __attribute__((address_space(3))) unsigned int u32_l;

__device__ __forceinline__ void gl_lds16(const void* g, void* l) {
  __builtin_amdgcn_global_load_lds((const u32_g*)g, (u32_l*)l, 16, 0, 0);
}

// =====================================================================
// Staged operand layout (bf16): logical Z[rows][K], row-blocks RB of 256,
// K-tiles T of 64:  chunk(row,k) at
//   off = ((RB*KT + T)*2 + s)*16384 + g*4096 + (row&255)*16 + e*2
// B cols expert-interleaved: p = (o>>5)*256+((o>>3)&3)*64+(e>>1)*16+(o&7)*2+(e&1)
//   => in-tile: e = fn*2+(l15&1), o = by*32 + wc*8 + (l15>>1)
// =====================================================================

// ---- 256-thread weight tile stage ----
__device__ void wtile256(const float* __restrict__ w, __hip_bfloat16* __restrict__ out,
                         int Kin, int KT, int Oin, int oblk, int u, char* LDS)
{
  int kt = u % KT;
  int yy = u / KT;
  int e = yy / oblk;
  int o0 = (yy - e * oblk) << 6;
  int k0 = kt << 6;
  float* t = (float*)LDS;  // [64][65]
  int tid = threadIdx.x;
  int tx = tid & 63, ty = tid >> 6;  // 64 x 4
#pragma unroll
  for (int i = 0; i < 16; ++i) {
    int k = k0 + ty + i * 4;
    int o = o0 + tx;
    float v = (k < Kin && o < Oin) ? w[((size_t)e * Kin + k) * Oin + o] : 0.f;
    t[(ty + i * 4) * 65 + tx] = v;
  }
  __syncthreads();
#pragma unroll
  for (int it = 0; it < 2; ++it) {
    int c = it * 256 + tid;
    int j = c & 63, sg = c >> 6;
    bf16x8 v;
#pragma unroll
    for (int e8 = 0; e8 < 8; ++e8) v[e8] = (__bf16)t[(sg * 8 + e8) * 65 + j];
    int o = o0 + j;
    int p = ((o >> 5) << 8) + (((o >> 3) & 3) << 6) + ((e >> 1) << 4) + ((o & 7) << 1) + (e & 1);
    size_t off = (((size_t)(p >> 8) * KT + kt) * 2 + (sg >> 2)) * 16384
               + (size_t)(sg & 3) * 4096 + (size_t)(p & 255) * 16;
    *(bf16x8*)((char*)out + off) = v;
  }
}

// ---- x0 staging unit: 256 chunks ----
__device__ void x0unit(int u, const float* __restrict__ cond, const float* __restrict__ lat,
                       __hip_bfloat16* __restrict__ out)
{
  int c = u * 256 + threadIdx.x;
  int RB = c / 10240;
  int r1 = c - RB * 10240;
  int T = r1 >> 11, r2 = r1 & 2047;
  int n = RB * 256 + (r2 & 255);
  int k0 = T * 64 + (r2 >> 10) * 32 + ((r2 >> 8) & 3) * 8;
  bf16x8 v;
#pragma unroll
  for (int e = 0; e < 8; ++e) {
    int k = k0 + e;
    float f = (k < 219) ? cond[(size_t)n * 219 + k]
            : (k < 283) ? lat[(size_t)n * 64 + (k - 219)] : 0.f;
    v[e] = (__bf16)f;
  }
  *(bf16x8*)((char*)out + (size_t)c * 16) = v;
}

// ---- x1 latent unit (T=8 of KT=9): 256 chunks ----
__device__ void x1lat(int u, const float* __restrict__ lat, __hip_bfloat16* __restrict__ out)
{
  int c = u * 256 + threadIdx.x;  // 0..32767
  int RB = c >> 11, r2 = c & 2047;
  int n = RB * 256 + (r2 & 255);
  int k0 = (r2 >> 10) * 32 + ((r2 >> 8) & 3) * 8;
  bf16x8 v;
#pragma unroll
  for (int e = 0; e < 8; ++e) v[e] = (__bf16)lat[(size_t)n * 64 + k0 + e];
  size_t off = ((size_t)RB * 9 + 8) * 32768 + (size_t)r2 * 16;
  *(bf16x8*)((char*)out + off) = v;
}

// ---- prepS: ALL staging, one wide kernel, every block independent ----
__global__ __launch_bounds__(256) void prepS(
    const float* __restrict__ latent, const float* __restrict__ condition,
    const float* __restrict__ w0, const float* __restrict__ w1, const float* __restrict__ w2,
    __hip_bfloat16* x0s, __hip_bfloat16* x1s,
    __hip_bfloat16* w0s, __hip_bfloat16* w1s, __hip_bfloat16* w2s)
{
  __shared__ __align__(16) char LDS[64 * 65 * 4];
  int b = blockIdx.x;
  if (b < 320)       wtile256(w0, w0s, 283, 5, 512, 8, b, LDS);
  else if (b < 896)  wtile256(w1, w1s, 576, 9, 512, 8, b - 320, LDS);
  else if (b < 1088) wtile256(w2, w2s, 512, 8, 171, 3, b - 896, LDS);
  else if (b < 1152) {
    int u0 = b - 1088;
    x1lat(u0, latent, x1s);
    x1lat(u0 + 64, latent, x1s);
  } else {
    x0unit(b - 1152, condition, latent, x0s);  // 640 units
  }
}

// ---- gate kernel: LDS-cached weights, 4x4 register-blocked, exact fp32 ----
__global__ __launch_bounds__(256) void gate_k(
    const float* __restrict__ phs, const float* __restrict__ lat,
    const float* __restrict__ gw1, const float* __restrict__ gb1,
    const float* __restrict__ gw2, const float* __restrict__ gb2,
    const float* __restrict__ gw3, const float* __restrict__ gb3,
    float* __restrict__ coeff)
{
  __shared__ __align__(16) float wL[128 * 128];   // 64KB, reused w1 -> w2
  __shared__ __align__(16) float g0T[104 * 36];   // [k][row]
  __shared__ __align__(16) float h1T[128 * 36];
  __shared__ __align__(16) float h2T[128 * 36];
  __shared__ __align__(16) float w3L[128 * 8];
  const int tid = threadIdx.x;
  const int n0 = blockIdx.x * 32;

  for (int i = tid; i < 104 * 32; i += 256) {
    int k = i >> 5, r = i & 31;
    g0T[k * 36 + r] = (k < 40) ? phs[(size_t)(n0 + r) * 40 + k]
                               : lat[(size_t)(n0 + r) * 64 + (k - 40)];
  }
  for (int i = tid; i < 104 * 32; i += 256) ((float4*)wL)[i] = ((const float4*)gw1)[i];
  ((float4*)w3L)[tid] = ((const float4*)gw3)[tid];
  __syncthreads();

  const int ct = tid & 31, rt = tid >> 5;
  const int c0 = ct << 2, r0 = rt << 2;

  // layer 1
  {
    f32x4 a0 = {}, a1 = {}, a2 = {}, a3 = {};
    for (int k = 0; k < 104; ++k) {
      f32x4 g = *(const f32x4*)&g0T[k * 36 + r0];
      f32x4 w = *(const f32x4*)&wL[k * 128 + c0];
      a0 += g * w.x; a1 += g * w.y; a2 += g * w.z; a3 += g * w.w;
    }
    f32x4 bb = *(const f32x4*)&gb1[c0];
    a0 += bb.x; a1 += bb.y; a2 += bb.z; a3 += bb.w;
#pragma unroll
    for (int j = 0; j < 4; ++j) {
      a0[j] = a0[j] > 0.f ? a0[j] : expm1f(a0[j]);
      a1[j] = a1[j] > 0.f ? a1[j] : expm1f(a1[j]);
      a2[j] = a2[j] > 0.f ? a2[j] : expm1f(a2[j]);
      a3[j] = a3[j] > 0.f ? a3[j] : expm1f(a3[j]);
    }
    *(f32x4*)&h1T[(c0 + 0) * 36 + r0] = a0;
    *(f32x4*)&h1T[(c0 + 1) * 36 + r0] = a1;
    *(f32x4*)&h1T[(c0 + 2) * 36 + r0] = a2;
    *(f32x4*)&h1T[(c0 + 3) * 36 + r0] = a3;
  }
  __syncthreads();
  for (int i = tid; i < 128 * 32; i += 256) ((float4*)wL)[i] = ((const float4*)gw2)[i];
  __syncthreads();

  // layer 2
  {
    f32x4 a0 = {}, a1 = {}, a2 = {}, a3 = {};
    for (int k = 0; k < 128; ++k) {
      f32x4 g = *(const f32x4*)&h1T[k * 36 + r0];
      f32x4 w = *(const f32x4*)&wL[k * 128 + c0];
      a0 += g * w.x; a1 += g * w.y; a2 += g * w.z; a3 += g * w.w;
    }
    f32x4 bb = *(const f32x4*)&gb2[c0];
    a0 += bb.x; a1 += bb.y; a2 += bb.z; a3 += bb.w;
#pragma unroll
    for (int j = 0; j < 4; ++j) {
      a0[j] = a0[j] > 0.f ? a0[j] : expm1f(a0[j]);
      a1[j] = a1[j] > 0.f ? a1[j] : expm1f(a1[j]);
      a2[j] = a2[j] > 0.f ? a2[j] : expm1f(a2[j]);
      a3[j] = a3[j] > 0.f ? a3[j] : expm1f(a3[j]);
    }
    *(f32x4*)&h2T[(c0 + 0) * 36 + r0] = a0;
    *(f32x4*)&h2T[(c0 + 1) * 36 + r0] = a1;
    *(f32x4*)&h2T[(c0 + 2) * 36 + r0] = a2;
    *(f32x4*)&h2T[(c0 + 3) * 36 + r0] = a3;
  }
  __syncthreads();

  // layer 3 + softmax
  {
    int row = tid >> 3, e = tid & 7;
    float acc = 0.f;
    for (int k = 0; k < 128; ++k) acc += h2T[k * 36 + row] * w3L[k * 8 + e];
    float lgt = acc + gb3[e];
    float m = lgt;
    m = fmaxf(m, __shfl_xor(m, 1));
    m = fmaxf(m, __shfl_xor(m, 2));
    m = fmaxf(m, __shfl_xor(m, 4));
    float ex = expf(lgt - m);
    float s = ex;
    s += __shfl_xor(s, 1);
    s += __shfl_xor(s, 2);
    s += __shfl_xor(s, 4);
    coeff[(size_t)(n0 + row) * 8 + e] = ex / s;
  }
}

// =====================================================================
// GEMM: 128x256 tile, ~48KB LDS single-buffer (m97 schedule), 2 blocks/CU.
// 8 waves: wr=wid>>2 (64-row half), wc=wid&3 (64-col quarter), acc[4][4].
// A tile = 128 rows = half an RB: per (s,g) segment take (bx&1)*2048 half.
// B tile = contiguous 32KB (staged layout IS the LDS image).
// MODE 0 -> staged bf16 next-layer activations; MODE 1 -> fp32 final out.
// =====================================================================
template <int KT, int KTD, int MODE>
__global__ __launch_bounds__(512, 4) void gemm_k(
    const __hip_bfloat16* __restrict__ Ap, const __hip_bfloat16* __restrict__ Bp,
    const float* __restrict__ coeff, const float* __restrict__ bias,
    __hip_bfloat16* __restrict__ dstS, float* __restrict__ dstF)
{
  __shared__ __align__(16) char lds[49152];   // A 16KB | B 32KB; epilogue overlays
  const int bid = blockIdx.x;
  const int bx = bid & 31;          // M-tile (128 rows), 32 tiles
  const int by = bid >> 5;          // N-tile (256 cols)
  const int tid = threadIdx.x;
  const int lane = tid & 63;
  const int wid = tid >> 6;
  const int wr = wid >> 2, wc = wid & 3;
  const int l15 = lane & 15, lg = lane >> 4;
  const int aHalf = (bx & 1) * 2048;

  const char* aG = (const char*)Ap + (size_t)(bx >> 1) * KT * 32768;
  const char* bG = (const char*)Bp + (size_t)by * KT * 32768;

  // stage K-tile T: A 16KB (2 chunks/thread, strided halves) + B 32KB (linear)
#define STAGE(T)                                                             \
  {                                                                          \
    const char* gA_ = aG + (size_t)(T) * 32768;                              \
    const char* gB_ = bG + (size_t)(T) * 32768;                              \
    _Pragma("unroll") for (int i = 0; i < 2; ++i) {                          \
      int c = i * 512 + tid;                                                 \
      gl_lds16(gA_ + (c >> 9) * 16384 + ((c >> 7) & 3) * 4096 + aHalf        \
                   + (c & 127) * 16,                                         \
               lds + c * 16);                                                \
    }                                                                        \
    _Pragma("unroll") for (int i = 0; i < 4; ++i) {                          \
      int c = i * 512 + tid;                                                 \
      gl_lds16(gB_ + c * 16, lds + 16384 + c * 16);                          \
    }                                                                        \
  }

  f32x4 acc[4][4] = {};

  STAGE(0);
  asm volatile("s_waitcnt vmcnt(0)" ::: "memory");
  __builtin_amdgcn_s_barrier();

#pragma unroll 1
  for (int t = 0; t < KT; ++t) {
#pragma unroll
    for (int s = 0; s < 2; ++s) {
      bf16x8 a[4], b[4];
#pragma unroll
      for (int fm = 0; fm < 4; ++fm)
        a[fm] = *(const bf16x8*)(lds + s * 8192 + lg * 2048
                                 + ((wr << 6) + fm * 16 + l15) * 16);
#pragma unroll
      for (int nf = 0; nf < 4; ++nf)
        b[nf] = *(const bf16x8*)(lds + 16384 + s * 16384 + lg * 4096
                                 + (wc << 10) + nf * 256 + l15 * 16);
#pragma unroll
      for (int fm = 0; fm < 4; ++fm)
#pragma unroll
        for (int nf = 0; nf < 4; ++nf)
          acc[fm][nf] = __builtin_amdgcn_mfma_f32_16x16x32_bf16(a[fm], b[nf], acc[fm][nf], 0, 0, 0);
    }
    if (t + 1 < KT) {
      __builtin_amdgcn_s_barrier();   // all waves done reading lds
      STAGE(t + 1);
      asm volatile("s_waitcnt vmcnt(0)" ::: "memory");
      __builtin_amdgcn_s_barrier();   // tile t+1 ready
    }
  }
#undef STAGE
  __syncthreads();  // lds reuse boundary

  // ---- fused expert-blend epilogue (coeff transposed [8][132]: conflict-free) ----
  float* cl2 = (float*)lds;                  // 8 x 132 f32 = 4224 B
  float* tb  = (float*)(lds + 4352);         // [128][33] f32 = 16896 B (MODE 0)
  {
#pragma unroll
    for (int i = 0; i < 2; ++i) {
      int idx = i * 512 + tid;               // 1024 = 128 rows x 8 experts
      int e = idx & 7, n = idx >> 3;
      cl2[e * 132 + n] = coeff[((size_t)bx * 128 + n) * 8 + e];
    }
  }
  __syncthreads();
  const int e0 = lane & 1;
  const int o_loc = (wc << 3) + (l15 >> 1);

  if (MODE == 0) {
    float bb[4];
#pragma unroll
    for (int fn = 0; fn < 4; ++fn) bb[fn] = bias[(fn * 2 + e0) * 512 + by * 32 + o_loc];
#pragma unroll
    for (int fm = 0; fm < 4; ++fm) {
#pragma unroll
      for (int r = 0; r < 4; ++r) {
        int n_loc = (wr << 6) + fm * 16 + (lg << 2) + r;
        float s = 0.f;
#pragma unroll
        for (int fn = 0; fn < 4; ++fn)
          s += cl2[(fn * 2 + e0) * 132 + n_loc] * (acc[fm][fn][r] + bb[fn]);
        s += __shfl_xor(s, 1);
        s = s > 0.f ? s : expm1f(s);
        if ((lane & 1) == (fm & 1)) tb[n_loc * 33 + o_loc] = s;
      }
    }
    __syncthreads();
    {
      int n_loc = tid & 127, c = tid >> 7;   // 512 chunks = 128 rows x 4 o-groups
      const float* p = &tb[n_loc * 33 + c * 8];
      bf16x8 v;
#pragma unroll
      for (int j = 0; j < 8; ++j) v[j] = (__bf16)p[j];
      size_t off = (((size_t)(bx >> 1) * KTD + (by >> 1)) * 2 + (by & 1)) * 16384
                 + (size_t)c * 4096 + (size_t)((bx & 1) * 128 + n_loc) * 16;
      *(bf16x8*)((char*)dstS + off) = v;
    }
  } else {
    const int o_g = by * 32 + o_loc;
    if (o_g < 171) {
      float bb[4];
#pragma unroll
      for (int fn = 0; fn < 4; ++fn) bb[fn] = bias[(fn * 2 + e0) * 171 + o_g];
#pragma unroll
      for (int fm = 0; fm < 4; ++fm) {
#pragma unroll
        for (int r = 0; r < 4; ++r) {
          int n_loc = (wr << 6) + fm * 16 + (lg << 2) + r;
          float s = 0.f;
#pragma unroll
          for (int fn = 0; fn < 4; ++fn)
            s += cl2[(fn * 2 + e0) * 132 + n_loc] * (acc[fm][fn][r] + bb[fn]);
          s += __shfl_xor(s, 1);
          if ((lane & 1) == (fm & 1))
            dstF[(size_t)(bx * 128 + n_loc) * 171 + o_g] = s;
        }
      }
    }
  }
}

// ---------------- launch ----------------
extern "C" void kernel_launch(void* const* d_in, const int* in_sizes, int n_in,
                              void* d_out, int out_size, void* d_ws, size_t ws_size,
                              hipStream_t stream)
{
  const float* latent    = (const float*)d_in[0];
  const float* condition = (const float*)d_in[1];
  const float* phase     = (const float*)d_in[2];
  const float* gw1 = (const float*)d_in[3];
  const float* gb1 = (const float*)d_in[4];
  const float* gw2 = (const float*)d_in[5];
  const float* gb2 = (const float*)d_in[6];
  const float* gw3 = (const float*)d_in[7];
  const float* gb3 = (const float*)d_in[8];
  const float* w0  = (const float*)d_in[9];
  const float* b0  = (const float*)d_in[10];
  const float* w1  = (const float*)d_in[11];
  const float* b1  = (const float*)d_in[12];
  const float* w2  = (const float*)d_in[13];
  const float* b2  = (const float*)d_in[14];

  float* out   = (float*)d_out;
  float* coeff = out + (size_t)NR * 171;

  char* ws = (char*)d_ws;
  __hip_bfloat16* x0s = (__hip_bfloat16*)ws; ws += (size_t)16 * 5 * 32768;
  __hip_bfloat16* x1s = (__hip_bfloat16*)ws; ws += (size_t)16 * 9 * 32768;
  __hip_bfloat16* x2s = (__hip_bfloat16*)ws; ws += (size_t)16 * 8 * 32768;
  __hip_bfloat16* w0s = (__hip_bfloat16*)ws; ws += (size_t)16 * 5 * 32768;
  __hip_bfloat16* w1s = (__hip_bfloat16*)ws; ws += (size_t)16 * 9 * 32768;
  __hip_bfloat16* w2s = (__hip_bfloat16*)ws; ws += (size_t)6 * 8 * 32768;

  // K1: gate (exact fp32, LDS-cached weights)
  gate_k<<<128, 256, 0, stream>>>(phase, latent, gw1, gb1, gw2, gb2, gw3, gb3, coeff);

  // K2: all staging in parallel
  prepS<<<1792, 256, 0, stream>>>(latent, condition, w0, w1, w2,
                                  x0s, x1s, w0s, w1s, w2s);

  // K3-K5: 128x256-tile fused GEMMs (2 blocks/CU co-residency)
  gemm_k<5, 9, 0><<<512, 512, 0, stream>>>(x0s, w0s, coeff, b0, x1s, nullptr);
  gemm_k<9, 8, 0><<<512, 512, 0, stream>>>(x1s, w1s, coeff, b1, x2s, nullptr);
  gemm_k<8, 0, 1><<<192, 512, 0, stream>>>(x2s, w2s, coeff, b2, nullptr, out);
}